// Round 4
// baseline (1517.317 us; speedup 1.0000x reference)
//
#include <hip/hip_runtime.h>
#include <cmath>

#define SEQ 32
#define BB 1024
#define II 2048
#define OO 1024

typedef unsigned short ushortt;
typedef short v8s __attribute__((ext_vector_type(8)));
typedef float v4f __attribute__((ext_vector_type(4)));

// ---------------- init: zero a float4 region ----------------
__global__ void zero_kernel(float4* __restrict__ p, int n4) {
  int i = blockIdx.x * blockDim.x + threadIdx.x;
  int stride = gridDim.x * blockDim.x;
  float4 z; z.x = z.y = z.z = z.w = 0.f;
  for (; i < n4; i += stride) p[i] = z;
}

__global__ void set_int_kernel(int* __restrict__ p, int val, int n) {
  int i = blockIdx.x * blockDim.x + threadIdx.x;
  if (i < n) p[i] = val;
}

// ---------------- fp32 transpose: dst[c*R+r] = src[r*C+c] ----------------
__global__ void transpose_f32(const float* __restrict__ src, float* __restrict__ dst,
                              int R, int C) {
  __shared__ float t[32][33];
  int c0 = blockIdx.x * 32, r0 = blockIdx.y * 32;
  int tx = threadIdx.x, ty = threadIdx.y;
#pragma unroll
  for (int k = 0; k < 4; k++)
    t[ty + k * 8][tx] = src[(long)(r0 + ty + k * 8) * C + c0 + tx];
  __syncthreads();
#pragma unroll
  for (int k = 0; k < 4; k++)
    dst[(long)(c0 + ty + k * 8) * R + r0 + tx] = t[tx][ty + k * 8];
}

// ---------------- x prep: xT bf16 [I][B] + column counts n[i] ----------------
__global__ void prep_x(const float* __restrict__ x, ushortt* __restrict__ xT,
                       float* __restrict__ nvec) {
  __shared__ ushortt t[32][33];
  int i0 = blockIdx.x * 32, b0 = blockIdx.y * 32;
  int tx = threadIdx.x, ty = threadIdx.y;
#pragma unroll
  for (int k = 0; k < 4; k++) {
    float val = x[(long)(b0 + ty + k * 8) * II + i0 + tx];
    ushortt us = (val != 0.0f) ? (ushortt)0x3F80 : (ushortt)0;  // bf16 1.0
    t[ty + k * 8][tx] = us;
    if (us) atomicAdd(&nvec[i0 + tx], 1.0f);  // exact integer counts in fp32
  }
  __syncthreads();
#pragma unroll
  for (int k = 0; k < 4; k++)
    xT[(long)(i0 + ty + k * 8) * BB + b0 + tx] = t[tx][ty + k * 8];
}

// ---------------- per-row active-index lists (ordered, deterministic) ----------------
__global__ void build_idx(const float* __restrict__ x, ushortt* __restrict__ idxArr,
                          int* __restrict__ cntArr) {
  int b = blockIdx.x;
  int lane = threadIdx.x;  // 64 threads = 1 wave
  const float* row = x + (long)b * II;
  int base = 0;
  for (int c = 0; c < II / 64; ++c) {
    float val = row[c * 64 + lane];
    unsigned long long m = __ballot(val != 0.0f);
    if (val != 0.0f) {
      int pos = base + __popcll(m & ((1ull << lane) - 1ull));
      if (pos < 256) idxArr[(b << 8) + pos] = (ushortt)(c * 64 + lane);
    }
    base += __popcll(m);
  }
  if (lane == 0) cntArr[b] = base < 256 ? base : 256;
}

// ---------------- K1: z_in gather + LIF, XCD-local o-slices ----------------
// grid 2048: blockIdx.x = bgroup*8 + ochunk, so ochunk == bid%8 pins each
// 1 MB wT slice (128 cols) to one XCD's L2 under round-robin dispatch.
// Each wave handles one batch row; spike list is wave-uniform (scalar loads).
__global__ __launch_bounds__(256) void step_kernel(
    const float* __restrict__ wT, const float* __restrict__ bias,
    const ushortt* __restrict__ idxArr, const int* __restrict__ cntArr,
    float* __restrict__ v, ushortt* __restrict__ zT, float* __restrict__ cvec,
    float vd, int last, float* __restrict__ outz, float* __restrict__ outv) {
  int bid = blockIdx.x;
  int ochunk = bid & 7;
  int bgroup = bid >> 3;
  int tid = threadIdx.x;
  int wave = tid >> 6, lane = tid & 63;
  int b = bgroup * 4 + wave;
  int coff = (ochunk * 128 + lane * 2) >> 1;  // float2 index within a wT row
  const ushortt* sIdx = idxArr + (b << 8);
  int cnt = cntArr[b];
  const float2* wT2 = (const float2*)wT;  // row = 512 float2
  float2 acc; acc.x = acc.y = 0.f;
  int j = 0;
  for (; j + 4 <= cnt; j += 4) {
    int i0 = sIdx[j], i1 = sIdx[j + 1], i2 = sIdx[j + 2], i3 = sIdx[j + 3];
    float2 a0 = wT2[(i0 << 9) + coff];
    float2 a1 = wT2[(i1 << 9) + coff];
    float2 a2 = wT2[(i2 << 9) + coff];
    float2 a3 = wT2[(i3 << 9) + coff];
    acc.x += a0.x; acc.y += a0.y;
    acc.x += a1.x; acc.y += a1.y;
    acc.x += a2.x; acc.y += a2.y;
    acc.x += a3.x; acc.y += a3.y;
  }
  for (; j < cnt; ++j) {
    float2 a = wT2[((int)sIdx[j] << 9) + coff];
    acc.x += a.x; acc.y += a.y;
  }
  float2 bi = ((const float2*)bias)[coff];
  float2 vv = ((const float2*)v)[(b << 9) + coff];
  float zin[2] = {acc.x + bi.x, acc.y + bi.y};
  float vr[2] = {vv.x, vv.y};
  float zo[2];
#pragma unroll
  for (int c2 = 0; c2 < 2; c2++) {
    float nv = vr[c2] * vd + zin[c2];
    float z = (nv >= 1.0f) ? 1.0f : 0.0f;
    nv = nv * (1.0f - z);
    vr[c2] = nv; zo[c2] = z;
    int o = coff * 2 + c2;
    zT[(o << 10) + b] = (z != 0.f) ? (ushortt)0x3F80 : (ushortt)0;
    if (z != 0.f) atomicAdd(&cvec[o], 1.0f);  // exact integer counts
  }
  float2 vout; vout.x = vr[0]; vout.y = vr[1];
  ((float2*)v)[(b << 9) + coff] = vout;
  if (last) {
    float2 zout; zout.x = zo[0]; zout.y = zo[1];
    ((float2*)outz)[(b << 9) + coff] = zout;
    ((float2*)outv)[(b << 9) + coff] = vout;
  }
}

// ---------------- K3 eager: MT = x^T z (bf16 MFMA, exact) + coalesced A/w RMW ----------------
// MT[i,o]; A_t = d*A + MT; wT[i,o] = clip(wT + 1e-3*(pt*c[o] + spre*MT) - 1e-3*(pt*n[i] + A_t))
// everSpike[tile]: while 0 (no o-col in this tile ever spiked), A==0 identically
// -> skip AT RMW; update reduces to w = clip(w - 1e-3*pt*n[i]) (bit-exact: 0-y == -y).
__global__ __launch_bounds__(256) void stdp_kernel(
    const ushortt* __restrict__ xT, const ushortt* __restrict__ zT,
    const float* __restrict__ cvec, const float* __restrict__ nvec,
    float* __restrict__ wT, float* __restrict__ AT, int* __restrict__ everSpike,
    float dec, float pt, float spre) {
  int bi0 = blockIdx.x * 64;  // i tile (32 blocks)
  int bo0 = blockIdx.y * 64;  // o tile (16 blocks)
  int tile = blockIdx.y * gridDim.x + blockIdx.x;
  int tid = threadIdx.x, lane = tid & 63, wv = tid >> 6;
  __shared__ float sC[64];
  __shared__ float sN[64];
  __shared__ int sFlag;
  __shared__ ushortt As[64 * 72];  // 64 i-rows x 64 k (pad 72, 16B-aligned rows)
  __shared__ ushortt Bs[64 * 72];  // 64 o-rows x 64 k
  __shared__ float Ms[64 * 68];    // M tile, [i][o], pad 68
  if (tid < 64) { sC[tid] = cvec[bo0 + tid]; sN[tid] = nvec[bi0 + tid]; }
  if (tid == 0) sFlag = 0;
  __syncthreads();
  if (tid < 64 && sC[tid] != 0.0f) sFlag = 1;
  __syncthreads();
  int spike = sFlag;
  int ever = everSpike[tile];
  int active = spike | ever;

  if (spike) {
    v4f acc0 = {0.f, 0.f, 0.f, 0.f}, acc1 = acc0, acc2 = acc0, acc3 = acc0;
    int arow = tid >> 2, acol = (tid & 3) * 16;
    int fr = lane & 15, foct = (lane >> 4) * 8;
    for (int kc = 0; kc < BB; kc += 64) {
      *(uint4*)&As[arow * 72 + acol]     = *(const uint4*)&xT[(long)(bi0 + arow) * BB + kc + acol];
      *(uint4*)&As[arow * 72 + acol + 8] = *(const uint4*)&xT[(long)(bi0 + arow) * BB + kc + acol + 8];
      *(uint4*)&Bs[arow * 72 + acol]     = *(const uint4*)&zT[(long)(bo0 + arow) * BB + kc + acol];
      *(uint4*)&Bs[arow * 72 + acol + 8] = *(const uint4*)&zT[(long)(bo0 + arow) * BB + kc + acol + 8];
      __syncthreads();
#pragma unroll
      for (int ks = 0; ks < 64; ks += 32) {
        v8s af = *(const v8s*)&As[(wv * 16 + fr) * 72 + ks + foct];
        acc0 = __builtin_amdgcn_mfma_f32_16x16x32_bf16(af, *(const v8s*)&Bs[(0 + fr) * 72 + ks + foct], acc0, 0, 0, 0);
        acc1 = __builtin_amdgcn_mfma_f32_16x16x32_bf16(af, *(const v8s*)&Bs[(16 + fr) * 72 + ks + foct], acc1, 0, 0, 0);
        acc2 = __builtin_amdgcn_mfma_f32_16x16x32_bf16(af, *(const v8s*)&Bs[(32 + fr) * 72 + ks + foct], acc2, 0, 0, 0);
        acc3 = __builtin_amdgcn_mfma_f32_16x16x32_bf16(af, *(const v8s*)&Bs[(48 + fr) * 72 + ks + foct], acc3, 0, 0, 0);
      }
      __syncthreads();
    }
    // stage M to LDS: C layout col=lane&15, row=(lane>>4)*4+reg
    int col = lane & 15;
    int r0 = (lane >> 4) * 4;
    v4f accs[4] = {acc0, acc1, acc2, acc3};
#pragma unroll
    for (int ot = 0; ot < 4; ot++)
#pragma unroll
      for (int reg = 0; reg < 4; reg++)
        Ms[(wv * 16 + r0 + reg) * 68 + ot * 16 + col] = accs[ot][reg];
  }
  __syncthreads();

  if (active) {
    // full epilogue with AT RMW
#pragma unroll
    for (int p = 0; p < 4; p++) {
      int r = p * 16 + (tid >> 4);
      int c4 = tid & 15;
      long base = (long)(bi0 + r) * OO + bo0 + c4 * 4;
      float4 a4 = *(float4*)&AT[base];
      float4 w4 = *(float4*)&wT[base];
      float ni = sN[r];
      float m[4];
      if (spike) {
#pragma unroll
        for (int k = 0; k < 4; k++) m[k] = Ms[r * 68 + c4 * 4 + k];
      } else {
#pragma unroll
        for (int k = 0; k < 4; k++) m[k] = 0.0f;
      }
      float* ap = &a4.x;
      float* wp = &w4.x;
#pragma unroll
      for (int k = 0; k < 4; k++) {
        float cv = sC[c4 * 4 + k];
        float atn = dec * ap[k] + m[k];
        float dw = 1e-3f * (pt * cv + spre * m[k]) - 1e-3f * (pt * ni + atn);
        float wval = fminf(fmaxf(wp[k] + dw, -1.0f), 1.0f);
        ap[k] = atn;
        wp[k] = wval;
      }
      *(float4*)&AT[base] = a4;
      *(float4*)&wT[base] = w4;
    }
    if (spike && tid == 0) everSpike[tile] = 1;
  } else {
    // A==0 fast path: w-only RMW
#pragma unroll
    for (int p = 0; p < 4; p++) {
      int r = p * 16 + (tid >> 4);
      int c4 = tid & 15;
      long base = (long)(bi0 + r) * OO + bo0 + c4 * 4;
      float4 w4 = *(float4*)&wT[base];
      float ni = sN[r];
      float dw = -(1e-3f * (pt * ni + 0.0f));
      float* wp = &w4.x;
#pragma unroll
      for (int k = 0; k < 4; k++)
        wp[k] = fminf(fmaxf(wp[k] + dw, -1.0f), 1.0f);
      *(float4*)&wT[base] = w4;
    }
  }
}

extern "C" void kernel_launch(void* const* d_in, const int* in_sizes, int n_in,
                              void* d_out, int out_size, void* d_ws, size_t ws_size,
                              hipStream_t stream) {
  const float* x = (const float*)d_in[0];     // [B, I] {0,1} fp32
  const float* w = (const float*)d_in[1];     // [O, I] fp32
  const float* bias = (const float*)d_in[2];  // [O]
  float* out = (float*)d_out;                 // z[B,O] | v[B,O] | w[O,I]

  char* ws = (char*)d_ws;
  float* wT = (float*)(ws + 0);                    // [I][O] 8 MB
  float* AT = (float*)(ws + 8388608);              // [I][O] 8 MB
  float* vbuf = (float*)(ws + 16777216);           // [B][O] 4 MB
  float* cbuf = (float*)(ws + 20971520);           // [32][O] 128 KB
  float* nvec = (float*)(ws + 21102592);           // [I] 8 KB
  int* cntArr = (int*)(ws + 21110784);             // [B] 4 KB
  ushortt* idxArr = (ushortt*)(ws + 21114880);     // [B][256] 512 KB
  ushortt* zT = (ushortt*)(ws + 21639168);         // [O][B] bf16 2 MB
  ushortt* xT = (ushortt*)(ws + 23736320);         // [I][B] bf16 4 MB
  int* everSpike = (int*)(ws + 27930624);          // [512] tiles

  // zero AT, v, c, n, cnt (contiguous region: 8388608 .. 21114880 = 12726272 B)
  zero_kernel<<<1024, 256, 0, stream>>>((float4*)(ws + 8388608), 12726272 / 16);
  set_int_kernel<<<2, 256, 0, stream>>>(everSpike, 0, 512);
  // wT = w^T
  transpose_f32<<<dim3(II / 32, OO / 32), dim3(32, 8), 0, stream>>>(w, wT, OO, II);
  // xT bf16 + n
  prep_x<<<dim3(II / 32, BB / 32), dim3(32, 8), 0, stream>>>(x, xT, nvec);
  // active index lists
  build_idx<<<BB, 64, 0, stream>>>(x, idxArr, cntArr);

  const float dec = (float)exp(-0.05);  // decay (same for pre/post/mem)
  float p = 1.0f, u = 1.0f;             // tpre values for x=0 / x=1 (fp32 recurrence, matches np)
  for (int t = 0; t < SEQ; ++t) {
    p = p * dec;
    u = u * dec;
    u = u + 1.0f;
    float spre = u - p;
    int last = (t == SEQ - 1) ? 1 : 0;
    step_kernel<<<2048, 256, 0, stream>>>(wT, bias, idxArr, cntArr, vbuf, zT,
                                          cbuf + t * OO, dec, last,
                                          out, out + BB * OO);
    stdp_kernel<<<dim3(II / 64, OO / 64), 256, 0, stream>>>(xT, zT, cbuf + t * OO,
                                                            nvec, wT, AT, everSpike,
                                                            dec, p, spre);
  }
  // final w = wT^T -> d_out[2M..4M)
  transpose_f32<<<dim3(OO / 32, II / 32), dim3(32, 8), 0, stream>>>(wT, out + 2 * BB * OO, II, OO);
}

// Round 5
// 916.844 us; speedup vs baseline: 1.6549x; 1.6549x over previous
//
#include <hip/hip_runtime.h>
#include <cmath>

#define SEQ 32
#define BB 1024
#define II 2048
#define OO 1024

typedef unsigned short ushortt;

// ---------------- nvec[i] = count of x[:,i] != 0 (exact integer in fp32) ----------------
__global__ void nvec_kernel(const float* __restrict__ x, float* __restrict__ nvec) {
  int i = blockIdx.x * 256 + threadIdx.x;  // grid 8 x 256 -> i in [0,2048)
  float s = 0.f;
  for (int b = 0; b < BB; ++b) s += (x[(long)b * II + i] != 0.f) ? 1.f : 0.f;
  nvec[i] = s;
}

// ---------------- per-row active-index lists (ordered, deterministic) ----------------
__global__ void build_idx(const float* __restrict__ x, ushortt* __restrict__ idxArr,
                          int* __restrict__ cntArr) {
  int b = blockIdx.x;
  int lane = threadIdx.x;  // 64 threads = 1 wave
  const float* row = x + (long)b * II;
  int base = 0;
  for (int c = 0; c < II / 64; ++c) {
    float val = row[c * 64 + lane];
    unsigned long long m = __ballot(val != 0.0f);
    if (val != 0.0f) {
      int pos = base + __popcll(m & ((1ull << lane) - 1ull));
      if (pos < 256) idxArr[(b << 8) + pos] = (ushortt)(c * 64 + lane);
    }
    base += __popcll(m);
  }
  if (lane == 0) cntArr[b] = base < 256 ? base : 256;
}

// ---------------- idxT[j][b]: j-major transpose, padded with II (zero-row index) ----------------
__global__ void build_idxT(const ushortt* __restrict__ idxArr, const int* __restrict__ cntArr,
                           ushortt* __restrict__ idxT) {
  int id = blockIdx.x * 256 + threadIdx.x;  // grid 1024 x 256 -> 256*1024 entries
  int j = id >> 10, b = id & 1023;
  idxT[id] = (j < cntArr[b]) ? idxArr[(b << 8) + j] : (ushortt)II;
}

// ---------------- fp32 transpose: dst[c*R+r] = src[r*C+c] ----------------
__global__ void transpose_f32(const float* __restrict__ src, float* __restrict__ dst,
                              int R, int C) {
  __shared__ float t[32][33];
  int c0 = blockIdx.x * 32, r0 = blockIdx.y * 32;
  int tx = threadIdx.x, ty = threadIdx.y;
#pragma unroll
  for (int k = 0; k < 4; k++)
    t[ty + k * 8][tx] = src[(long)(r0 + ty + k * 8) * C + c0 + tx];
  __syncthreads();
#pragma unroll
  for (int k = 0; k < 4; k++)
    dst[(long)(c0 + ty + k * 8) * R + r0 + tx] = t[tx][ty + k * 8];
}

// ---------------- the whole 32-step simulation: one block per output column o ----------------
// Block o owns w[:,o], A[:,o], v[:,o] in LDS for all 32 steps. Everything it needs is local
// (c[o], M[:,o] from its own spike list + x rows); idx lists / nvec / x are read-only global.
__global__ __launch_bounds__(256, 4) void snn_kernel(
    const float* __restrict__ x, const float* __restrict__ w,
    const float* __restrict__ bias, const float* __restrict__ nvec,
    const ushortt* __restrict__ idxT, const int* __restrict__ cntArr,
    float* __restrict__ zC, float* __restrict__ vC, float* __restrict__ outw,
    float dec) {
  int o = blockIdx.x;
  int tid = threadIdx.x;
  int lane = tid & 63, wave = tid >> 6;

  __shared__ float wL[II + 1];  // +1: zero row for padded idx
  __shared__ float aL[II];
  __shared__ float mL[II];
  __shared__ float vL[BB];
  __shared__ int sList[BB];
  __shared__ int sCnt;

  // init: w column o = row o of w[O][I] (contiguous, coalesced)
#pragma unroll
  for (int q = 0; q < II / 256; ++q) wL[q * 256 + tid] = w[(long)o * II + q * 256 + tid];
  if (tid == 0) wL[II] = 0.f;
#pragma unroll
  for (int q = 0; q < II / 256; ++q) aL[q * 256 + tid] = 0.f;
#pragma unroll
  for (int k = 0; k < 4; ++k) vL[k * 256 + tid] = 0.f;

  // wave-uniform max cnt per (k, wave) chunk of 64 b's
  int jmax[4];
#pragma unroll
  for (int k = 0; k < 4; ++k) {
    int c = cntArr[k * 256 + wave * 64 + lane];
#pragma unroll
    for (int off = 32; off > 0; off >>= 1) c = max(c, __shfl_xor(c, off));
    jmax[k] = c;
  }
  float bo = bias[o];

  float zout[4], vout[4];
  float p = 1.f, u = 1.f;
  for (int t = 0; t < SEQ; ++t) {
    p = p * dec;
    u = u * dec;
    u = u + 1.f;
    float spre = u - p;
    __syncthreads();  // wL stable from previous update

    // gather + LIF (j-order sequential sum: identical order to prior passing rounds)
    float zk[4];
#pragma unroll
    for (int k = 0; k < 4; ++k) {
      int b = k * 256 + tid;
      float acc = 0.f;
      const ushortt* ip = idxT + b;
      int jm = jmax[k];
#pragma unroll 4
      for (int j = 0; j < jm; ++j) {
        int idx = ip[(long)j * BB];   // coalesced: lanes = consecutive b
        acc += wL[idx];               // random bank, ~2-way: free; pad lanes hit zero row (broadcast)
      }
      float zin = acc + bo;
      float nv = vL[b] * dec + zin;
      float z = (nv >= 1.f) ? 1.f : 0.f;
      nv = nv * (1.f - z);
      vL[b] = nv;
      zk[k] = z;
      if (t == SEQ - 1) { zout[k] = z; vout[k] = nv; }
    }

    // spike list for own column
    if (tid == 0) sCnt = 0;
    __syncthreads();
#pragma unroll
    for (int k = 0; k < 4; ++k) {
      if (zk[k] != 0.f) {
        int pos = atomicAdd(&sCnt, 1);
        sList[pos] = k * 256 + tid;
      }
    }
    __syncthreads();
    int ns = sCnt;  // block-uniform

    if (ns > 0) {
      // M[:,o] = sum over spiking b of x[b,:]  (exact integer counts)
#pragma unroll
      for (int q = 0; q < II / 256; ++q) mL[q * 256 + tid] = 0.f;
      __syncthreads();
      for (int s = 0; s < ns; ++s) {
        int b = sList[s];
#pragma unroll
        for (int q = 0; q < II / 256; ++q) {
          int i = q * 256 + tid;
          float xv = x[(long)b * II + i];
          if (xv != 0.f) mL[i] += 1.f;
        }
      }
      __syncthreads();
    }

    // STDP + weight update (same expression shape as prior passing rounds)
    float cv = (float)ns;
    float pt = p;
#pragma unroll
    for (int q = 0; q < II / 256; ++q) {
      int i = q * 256 + tid;
      float a0 = aL[i];
      float mt = (ns > 0) ? mL[i] : 0.f;
      float atn = dec * a0 + mt;
      float ni = nvec[i];
      float dw = 1e-3f * (pt * cv + spre * mt) - 1e-3f * (pt * ni + atn);
      float wv = wL[i] + dw;
      wv = fminf(fmaxf(wv, -1.f), 1.f);
      aL[i] = atn;
      wL[i] = wv;
    }
  }

  __syncthreads();
  // final writes: w row coalesced; z/v to column-major temporaries (coalesced), transposed after
#pragma unroll
  for (int q = 0; q < II / 256; ++q) outw[(long)o * II + q * 256 + tid] = wL[q * 256 + tid];
#pragma unroll
  for (int k = 0; k < 4; ++k) {
    int b = k * 256 + tid;
    zC[(long)o * BB + b] = zout[k];
    vC[(long)o * BB + b] = vout[k];
  }
}

extern "C" void kernel_launch(void* const* d_in, const int* in_sizes, int n_in,
                              void* d_out, int out_size, void* d_ws, size_t ws_size,
                              hipStream_t stream) {
  const float* x = (const float*)d_in[0];     // [B, I] {0,1} fp32
  const float* w = (const float*)d_in[1];     // [O, I] fp32
  const float* bias = (const float*)d_in[2];  // [O]
  float* out = (float*)d_out;                 // z[B,O] | v[B,O] | w[O,I]

  char* ws = (char*)d_ws;
  ushortt* idxArr = (ushortt*)(ws + 0);        // [B][256] 512 KB
  int* cntArr = (int*)(ws + 524288);           // [B] 4 KB
  ushortt* idxT = (ushortt*)(ws + 528384);     // [256][B] 512 KB
  float* nvec = (float*)(ws + 1052672);        // [I] 8 KB
  float* zC = (float*)(ws + 1060864);          // [O][B] 4 MB
  float* vC = (float*)(ws + 5255168);          // [O][B] 4 MB

  nvec_kernel<<<8, 256, 0, stream>>>(x, nvec);
  build_idx<<<BB, 64, 0, stream>>>(x, idxArr, cntArr);
  build_idxT<<<1024, 256, 0, stream>>>(idxArr, cntArr, idxT);

  const float dec = (float)exp(-0.05);  // shared decay (pre/post/mem), fp32 as before

  snn_kernel<<<OO, 256, 0, stream>>>(x, w, bias, nvec, idxT, cntArr,
                                     zC, vC, out + 2 * BB * OO, dec);

  // z, v: [O][B] -> [B][O]
  transpose_f32<<<dim3(BB / 32, OO / 32), dim3(32, 8), 0, stream>>>(zC, out, OO, BB);
  transpose_f32<<<dim3(BB / 32, OO / 32), dim3(32, 8), 0, stream>>>(vC, out + BB * OO, OO, BB);
}